// Round 6
// baseline (297.452 us; speedup 1.0000x reference)
//
#include <hip/hip_runtime.h>
#include <hip/hip_bf16.h>
#include <stdint.h>

#define BB 32768
#define NN 512
#define CG1 4
#define CG2 3
#define NTILE 10
#define NKC 32

typedef __attribute__((ext_vector_type(8))) short bf16x8;
typedef __attribute__((ext_vector_type(4))) float f32x4;

__device__ __forceinline__ void gld_lds16(const void* g, void* l) {
  typedef __attribute__((address_space(1))) const unsigned int gas_u32;
  typedef __attribute__((address_space(3))) unsigned int las_u32;
  __builtin_amdgcn_global_load_lds((gas_u32*)(uintptr_t)g,
                                   (las_u32*)(uint32_t)(uintptr_t)l, 16, 0, 0);
}

__device__ __forceinline__ unsigned short f2bf(float x) {
  __hip_bfloat16 h = __float2bfloat16(x);
  return *reinterpret_cast<unsigned short*>(&h);
}

__device__ __forceinline__ float bf2f(unsigned short u) {
  return __uint_as_float(((unsigned)u) << 16);
}

__device__ __forceinline__ float wave_reduce(float v) {
#pragma unroll
  for (int off = 32; off > 0; off >>= 1) v += __shfl_xor(v, off, 64);
  return v;
}

__device__ __forceinline__ float block_reduce(float v, float* red) {
  v = wave_reduce(v);
  const int wv = threadIdx.x >> 6, ln = threadIdx.x & 63;
  if (ln == 0) red[wv] = v;
  __syncthreads();
  if (threadIdx.x == 0) {
    float a = 0;
#pragma unroll
    for (int i = 0; i < 8; ++i) a += red[i];
    red[15] = a;
  }
  __syncthreads();
  return red[15];
}

// CG on Gamma v = SR, bf16 Gamma, 512 threads, symmetric column-major matvec.
// sm needs 2576 floats. Proven in R4 (absmax 0.0 at 4+3 iters).
__device__ void cg_phase(const unsigned short* __restrict__ Gbf, const float* __restrict__ SR,
                         float* __restrict__ st, float* __restrict__ v_out,
                         float* sm, int first, int iters) {
  float* sp = sm;
  float* apw = sm + 512;
  float* red = sm + 2560;
  const int t = threadIdx.x;
  const int rg = t >> 7;         // 0..3, wave-uniform
  const int c0 = (t & 127) * 4;  // 4 columns owned
  float x, r, p, rr;
  if (first) {
    float s = SR[t];
    x = 0.f; r = s; p = s;
    rr = block_reduce(s * s, red);
  } else {
    x = st[t]; r = st[512 + t]; p = st[1024 + t]; rr = st[1536];
  }
  for (int it = 0; it < iters; ++it) {
    sp[t] = p;
    __syncthreads();
    float a0 = 0, a1 = 0, a2 = 0, a3 = 0;
    for (int j = 0; j < NN; j += 32) {
#pragma unroll
      for (int jj = 0; jj < 8; ++jj) {
        const int row = j + jj * 4 + rg;
        ushort4 u = *(const ushort4*)(Gbf + row * NN + c0);
        float pv = sp[row];
        a0 += bf2f(u.x) * pv; a1 += bf2f(u.y) * pv;
        a2 += bf2f(u.z) * pv; a3 += bf2f(u.w) * pv;
      }
    }
    *(float4*)(apw + rg * 512 + c0) = make_float4(a0, a1, a2, a3);
    __syncthreads();
    float ap = apw[t] + apw[512 + t] + apw[1024 + t] + apw[1536 + t];
    float pAp = block_reduce(sp[t] * ap, red);
    float alpha = rr / pAp;
    x += alpha * sp[t];
    r -= alpha * ap;
    float rrn = block_reduce(r * r, red);
    float beta = rrn / rr;
    float pn = r + beta * sp[t];
    rr = rrn;
    __syncthreads();
    sp[t] = pn;  // safe: all reads of sp this iter are done
    p = pn;
    __syncthreads();
  }
  if (v_out) {
    v_out[t] = x;
  } else {
    st[t] = x; st[512 + t] = r; st[1024 + t] = p;
    if (t == 0) st[1536] = rr;
  }
}

// K1: block 0: CG phase 1 (4 bf16 iters; waits for converters). blocks 1..8:
//     Gamma -> bf16. blocks 9..1032: r = exp(sigma-lsh) -> bf16 transposed
//     Rt[N][B] + colsum buckets.
__global__ __launch_bounds__(512) void k1_rexp(
    const float* __restrict__ lsh, const float* __restrict__ sig,
    const float* __restrict__ SR, const float* __restrict__ Gamma,
    unsigned short* __restrict__ Rt, float* __restrict__ colsum,
    float* __restrict__ cgst, unsigned short* __restrict__ Gbf,
    int* __restrict__ gbf_ready) {
  __shared__ __align__(16) float sm[3328];
  const int t = threadIdx.x;
  if (blockIdx.x == 0) {
    if (t == 0) {
      while (__hip_atomic_load(gbf_ready, __ATOMIC_ACQUIRE, __HIP_MEMORY_SCOPE_AGENT) < 8)
        __builtin_amdgcn_s_sleep(8);
    }
    __syncthreads();
    cg_phase(Gbf, SR, cgst, nullptr, sm, 1, CG1);
    return;
  }
  if (blockIdx.x <= 8) {  // Gamma -> bf16, 64 rows per block
    const int cb = blockIdx.x - 1;
    const float4* src = (const float4*)(Gamma + (size_t)cb * 64 * NN);
    ushort4* dst = (ushort4*)(Gbf + (size_t)cb * 64 * NN);
    for (int i = t; i < 8192; i += 512) {
      float4 g = src[i];
      dst[i] = make_ushort4(f2bf(g.x), f2bf(g.y), f2bf(g.z), f2bf(g.w));
    }
    __threadfence();
    __syncthreads();
    if (t == 0)
      __hip_atomic_fetch_add(gbf_ready, 1, __ATOMIC_ACQ_REL, __HIP_MEMORY_SCOPE_AGENT);
    return;
  }
  // ---- worker: transpose + exp (R4-proven structure) ----
  unsigned short* tile = (unsigned short*)sm;  // [64 j][36 b]
  float* scr = sm + 1152;                      // [32][68]
  const int tc = t & 15, tg = t >> 4;
  const int wb = blockIdx.x - 9;
  const int bb = wb * 32;
  const int jl = t >> 3, bc = (t & 7) * 4;
  const size_t rowbase = (size_t)(bb + tg) * NN + 4 * tc;
  float4 sv = *(const float4*)(sig + rowbase);
  float4 lv = *(const float4*)(lsh + rowbase);
  for (int jt = 0; jt < 8; ++jt) {
    const int j0 = jt * 64;
    float r0 = __expf(sv.x - lv.x), r1 = __expf(sv.y - lv.y);
    float r2 = __expf(sv.z - lv.z), r3 = __expf(sv.w - lv.w);
    if (jt < 7) {  // prefetch next chunk before the barrier
      sv = *(const float4*)(sig + rowbase + 64 * (jt + 1));
      lv = *(const float4*)(lsh + rowbase + 64 * (jt + 1));
    }
    scr[tg * 68 + 4 * tc + 0] = r0;
    scr[tg * 68 + 4 * tc + 1] = r1;
    scr[tg * 68 + 4 * tc + 2] = r2;
    scr[tg * 68 + 4 * tc + 3] = r3;
    tile[(4 * tc + 0) * 36 + tg] = f2bf(r0);
    tile[(4 * tc + 1) * 36 + tg] = f2bf(r1);
    tile[(4 * tc + 2) * 36 + tg] = f2bf(r2);
    tile[(4 * tc + 3) * 36 + tg] = f2bf(r3);
    __syncthreads();
    {
      ushort4 vv = *(const ushort4*)(tile + jl * 36 + bc);
      *(ushort4*)(Rt + (size_t)(j0 + jl) * BB + bb + bc) = vv;
    }
    if (t < 64) {
      float sacc = 0;
#pragma unroll
      for (int g = 0; g < 32; ++g) sacc += scr[g * 68 + t];
      atomicAdd(&colsum[(wb & 7) * NN + j0 + t], sacc);
    }
    __syncthreads();
  }
}

// K2: block 0: CG phase 2 -> v, set v_ready. blocks 1..320: C-tile = Rt_i*Rt_j^T
//     over 1024-wide K-chunk (fp32 acc), then contract in-register against
//     Gamma and v -> one atomicAdd per block. Last block folds the loss.
__global__ __launch_bounds__(512) void k2_syrk(
    const unsigned short* __restrict__ Rt, const float* __restrict__ Gamma,
    const unsigned short* __restrict__ Gbf, const float* __restrict__ SR,
    const int* __restrict__ kp, float* __restrict__ cgst,
    float* __restrict__ v, int* __restrict__ v_ready,
    const float* __restrict__ colsum, float* __restrict__ secsum,
    int* __restrict__ done, float* __restrict__ out) {
  __shared__ __align__(16) unsigned short smem[16384];  // As[128][64], Bs[128][64]
  __shared__ int amlast;
  const int t = threadIdx.x;
  if (blockIdx.x == 0) {
    cg_phase(Gbf, nullptr, cgst, v, (float*)smem, 0, CG2);
    __syncthreads();
    if (t == 0) {
      __threadfence();
      __hip_atomic_store(v_ready, 1, __ATOMIC_RELEASE, __HIP_MEMORY_SCOPE_AGENT);
    }
    return;
  }
  const int wb = blockIdx.x - 1;
  const int kc = wb / NTILE, tt = wb % NTILE;
  const int ti = (int)((0x3221110000ULL >> (4 * tt)) & 0xF);
  const int tj = (int)((0x3323213210ULL >> (4 * tt)) & 0xF);
  const int i0 = ti * 128, j0 = tj * 128;
  const int diag = (ti == tj);
  const size_t b0 = (size_t)kc * 1024;
  const int lane = t & 63, wv = t >> 6;
  const int wi = (wv & 3) * 32, wj = (wv >> 2) * 64;
  const int lm = lane & 15, lq = lane >> 4;
  unsigned short* As = smem;
  unsigned short* Bs = diag ? smem : smem + 8192;
  const int srow = t >> 3, scol = (t & 7) * 8;
  f32x4 acc[2][4];
#pragma unroll
  for (int a = 0; a < 2; ++a)
#pragma unroll
    for (int b = 0; b < 4; ++b) acc[a][b] = (f32x4){0.f, 0.f, 0.f, 0.f};

  for (int ks = 0; ks < 16; ++ks) {
    const size_t bcur = b0 + ks * 64;
    gld_lds16(Rt + (size_t)(i0 + srow) * BB + bcur + scol, As + srow * 64 + scol);
    gld_lds16(Rt + (size_t)(i0 + 64 + srow) * BB + bcur + scol, As + (64 + srow) * 64 + scol);
    if (!diag) {
      gld_lds16(Rt + (size_t)(j0 + srow) * BB + bcur + scol, Bs + srow * 64 + scol);
      gld_lds16(Rt + (size_t)(j0 + 64 + srow) * BB + bcur + scol, Bs + (64 + srow) * 64 + scol);
    }
    __syncthreads();
#pragma unroll
    for (int s = 0; s < 2; ++s) {
      bf16x8 af[2], bfr[4];
#pragma unroll
      for (int g = 0; g < 2; ++g)
        af[g] = *(const bf16x8*)(As + (wi + g * 16 + lm) * 64 + s * 32 + lq * 8);
#pragma unroll
      for (int g = 0; g < 4; ++g)
        bfr[g] = *(const bf16x8*)(Bs + (wj + g * 16 + lm) * 64 + s * 32 + lq * 8);
#pragma unroll
      for (int gm = 0; gm < 2; ++gm)
#pragma unroll
        for (int gn = 0; gn < 4; ++gn)
          acc[gm][gn] = __builtin_amdgcn_mfma_f32_16x16x32_bf16(af[gm], bfr[gn], acc[gm][gn], 0, 0, 0);
    }
    __syncthreads();
  }
  // ---- epilogue: wait for v (usually already set), contract tile in-register ----
  if (t == 0) {
    while (!__hip_atomic_load(v_ready, __ATOMIC_ACQUIRE, __HIP_MEMORY_SCOPE_AGENT))
      __builtin_amdgcn_s_sleep(8);
  }
  __syncthreads();
  float* sv = (float*)smem;   // 512 floats (LDS reuse)
  float* red = sv + 512;      // 16 floats
  sv[t] = v[t];
  __syncthreads();
  // C/D layout: col = lane&15, row = (lane>>4)*4 + reg
  float s = 0;
#pragma unroll
  for (int gm = 0; gm < 2; ++gm) {
    const int rbase = i0 + wi + gm * 16 + lq * 4;
#pragma unroll
    for (int gn = 0; gn < 4; ++gn) {
      const int col = j0 + wj + gn * 16 + lm;
      const float vc = sv[col];
#pragma unroll
      for (int e = 0; e < 4; ++e) {
        const int row = rbase + e;
        s += sv[row] * Gamma[(size_t)row * NN + col] * acc[gm][gn][e] * vc;
      }
    }
  }
  if (!diag) s *= 2.f;
  float stot = block_reduce(s, red);
  if (t == 0) {
    atomicAdd(secsum, stot);
    __threadfence();
    int tk = __hip_atomic_fetch_add(done, 1, __ATOMIC_ACQ_REL, __HIP_MEMORY_SCOPE_AGENT);
    amlast = (tk == NKC * NTILE - 1);
  }
  __syncthreads();
  if (!amlast) return;
  // ---- final fold (last block) ----
  float cs = 0;
#pragma unroll
  for (int bk = 0; bk < 8; ++bk) cs += colsum[bk * NN + t];
  float f = (cs * (1.0f / BB)) * sv[t] * SR[t];
  float first = block_reduce(f, red);
  if (t == 0) {
    float kk = (float)kp[0];
    float sec = __hip_atomic_load(secsum, __ATOMIC_RELAXED, __HIP_MEMORY_SCOPE_AGENT);
    out[0] = -(first / kk - sec / ((float)BB * 2.0f * kk));
  }
}

extern "C" void kernel_launch(void* const* d_in, const int* in_sizes, int n_in,
                              void* d_out, int out_size, void* d_ws, size_t ws_size,
                              hipStream_t stream) {
  const float* lsh = (const float*)d_in[0];
  const float* sig = (const float*)d_in[1];
  const float* SR = (const float*)d_in[2];
  const float* Gam = (const float*)d_in[3];
  const int* kp = (const int*)d_in[4];
  char* ws = (char*)d_ws;
  // layout: F small region 32KB | Gbf 512KB | Rt 32MB
  float* F = (float*)ws;
  float* colsum = F;                 // [4096]
  float* secsum = F + 4096;          // [1]
  int* done = (int*)(F + 4100);      // [1]
  int* v_ready = (int*)(F + 4104);   // [1]
  int* gbf_ready = (int*)(F + 4108); // [1]
  float* cgst = F + 4160;            // [1600]
  float* v = F + 5760;               // [512]
  unsigned short* Gbf = (unsigned short*)(ws + 32768);
  unsigned short* Rt = (unsigned short*)(ws + 32768 + (512 << 10));

  hipMemsetAsync(F, 0, 4224 * sizeof(float), stream);
  k1_rexp<<<1033, 512, 0, stream>>>(lsh, sig, SR, Gam, Rt, colsum, cgst, Gbf, gbf_ready);
  k2_syrk<<<1 + NKC * NTILE, 512, 0, stream>>>(Rt, Gam, Gbf, SR, kp, cgst, v, v_ready,
                                               colsum, secsum, done, (float*)d_out);
}